// Round 6
// baseline (52289.709 us; speedup 1.0000x reference)
//
#include <hip/hip_runtime.h>
#include <hip/hip_bf16.h>
#include <math.h>

#define GBK 512          // grid blocks (2 per CU, co-resident)
#define NT  512          // threads per block (8 waves)

constexpr int T_STEPS = 600;
constexpr int TXT     = 200;
constexpr int NMEL    = 80;
constexpr int H       = 1024;
constexpr int ATT     = 640;
constexpr int DIN     = H + ATT;   // 1664
constexpr int NGRP    = 32;        // wakeup lines
constexpr int GRPSZ   = GBK / NGRP;
constexpr int DET     = 511;       // detector block
constexpr int GATE_B  = 500;       // gate-output block
constexpr int ATT_B0  = 20;        // attention blocks 20..23
constexpr int NATT    = 4;

// ---- ws layout: bf16 region (ushort element offsets) ----
constexpr size_t O_WQ    = 0;                                  // 640*1024
constexpr size_t O_WIHA  = O_WQ   + (size_t)ATT*H;             // 4096*80
constexpr size_t O_WIH0  = O_WIHA + (size_t)4*H*NMEL;          // 4096*1664
constexpr size_t O_WHH1  = O_WIH0 + (size_t)4*H*DIN;           // 4096*1024
constexpr size_t O_WD1   = O_WHH1 + (size_t)4*H*H;             // 1024*1024
constexpr size_t O_WD2   = O_WD1  + (size_t)H*H;
constexpr size_t O_KEYS  = O_WD2  + (size_t)H*H;               // 200*640
constexpr size_t O_VALS  = O_KEYS + (size_t)TXT*ATT;
constexpr size_t O_END_U = O_VALS + (size_t)TXT*ATT;
constexpr size_t FBYTE   = ((O_END_U*2 + 255)/256)*256;        // float region start
// ---- float region (float element offsets) ----
constexpr int F_X   = 0;             // 128 (80 used)
constexpr int F_HA  = 128;           // 2*H ping-pong
constexpr int F_H0  = F_HA + 2*H;    // H
constexpr int F_H1  = F_H0 + H;      // 2*H ping-pong
constexpr int F_Q   = F_H1 + 2*H;    // ATT
constexpr int F_D1  = F_Q  + ATT;    // H
constexpr int F_D   = F_D1 + H;      // H
constexpr int F_AZ4 = F_D  + H;      // 16 (4 used: partial sum-exp)
constexpr int F_CP4 = F_AZ4 + 16;    // 4*ATT unnormalized ctx partials
constexpr int F_END = F_CP4 + 4*ATT;
constexpr size_t BBYTE  = FBYTE + (((size_t)F_END*4 + 255)/256)*256;
// barrier region (uint offsets): per-block flags (16B stride), lgen lines, gang flags
constexpr int LGEN_OFF = GBK*4;             // 32 lines x 64 uints
constexpr int GFLG_OFF = GBK*4 + NGRP*64;   // 16 flags x 4 uints
constexpr int BAR_N    = GFLG_OFF + 16*4;

typedef unsigned short ushortT;
typedef ushortT us4 __attribute__((ext_vector_type(4)));

__device__ __forceinline__ float bf2f(ushortT u) {
  return __uint_as_float(((unsigned)u) << 16);
}
__device__ __forceinline__ ushortT f2bf(float x) {
  __hip_bfloat16 h = __float2bfloat16(x);
  ushortT u; __builtin_memcpy(&u, &h, 2); return u;
}
__device__ __forceinline__ us4 cvt4(float4 a) {
  return us4{ f2bf(a.x), f2bf(a.y), f2bf(a.z), f2bf(a.w) };
}
__device__ __forceinline__ float sigf(float x) { return 1.0f / (1.0f + expf(-x)); }

__device__ __forceinline__ float red64(float v) {
  #pragma unroll
  for (int off = 32; off > 0; off >>= 1) v += __shfl_xor(v, off, 64);
  return v;
}

// coherent (agent-scope, cache-bypassing) accessors for dynamic cross-block data
__device__ __forceinline__ float cload(const float* p) {
  return __hip_atomic_load(p, __ATOMIC_RELAXED, __HIP_MEMORY_SCOPE_AGENT);
}
__device__ __forceinline__ void cstore(float* p, float v) {
  __hip_atomic_store(p, v, __ATOMIC_RELAXED, __HIP_MEMORY_SCOPE_AGENT);
}
__device__ __forceinline__ void cstage(float* dst, const float* src, int n) {
  for (int i = threadIdx.x; i < n; i += NT) dst[i] = cload(src + i);
}
__device__ __forceinline__ unsigned aload(const unsigned* p) {
  return __hip_atomic_load(p, __ATOMIC_RELAXED, __HIP_MEMORY_SCOPE_AGENT);
}
__device__ __forceinline__ void astore(unsigned* p, unsigned v) {
  __hip_atomic_store(p, v, __ATOMIC_RELAXED, __HIP_MEMORY_SCOPE_AGENT);
}

// ---- conflict-free dots: lane handles float4 index c*64+lane ----
__device__ __forceinline__ float dotbf(const ushortT* __restrict__ Wrow,
                                       const float* __restrict__ v, int lane) {
  const us4* w4 = (const us4*)Wrow;
  const float4* v4 = (const float4*)v;
  float s = 0.f;
  #pragma unroll
  for (int c = 0; c < 4; ++c) {
    us4 w = w4[c*64 + lane];
    float4 x = v4[c*64 + lane];
    s += bf2f(w[0])*x.x + bf2f(w[1])*x.y + bf2f(w[2])*x.z + bf2f(w[3])*x.w;
  }
  return s;
}
__device__ __forceinline__ float dot640bf(const ushortT* __restrict__ Wrow,
                                          const float* __restrict__ v, int lane) {
  const us4* w4 = (const us4*)Wrow;
  const float4* v4 = (const float4*)v;
  float s = 0.f;
  #pragma unroll
  for (int c = 0; c < 2; ++c) {
    us4 w = w4[c*64 + lane];
    float4 x = v4[c*64 + lane];
    s += bf2f(w[0])*x.x + bf2f(w[1])*x.y + bf2f(w[2])*x.z + bf2f(w[3])*x.w;
  }
  if (lane < 32) {
    us4 w = w4[128 + lane];
    float4 x = v4[128 + lane];
    s += bf2f(w[0])*x.x + bf2f(w[1])*x.y + bf2f(w[2])*x.z + bf2f(w[3])*x.w;
  }
  return s;
}
__device__ __forceinline__ float dotf(const float* __restrict__ Wrow,
                                      const float* __restrict__ v, int lane) {
  const float4* w4 = (const float4*)Wrow;
  const float4* v4 = (const float4*)v;
  float s = 0.f;
  #pragma unroll
  for (int c = 0; c < 4; ++c) {
    float4 w = w4[c*64 + lane], x = v4[c*64 + lane];
    s += w.x*x.x + w.y*x.y + w.z*x.z + w.w*x.w;
  }
  return s;
}
__device__ __forceinline__ float dot640f(const float* __restrict__ Wrow,
                                         const float* __restrict__ v, int lane) {
  const float4* w4 = (const float4*)Wrow;
  const float4* v4 = (const float4*)v;
  float s = 0.f;
  #pragma unroll
  for (int c = 0; c < 2; ++c) {
    float4 w = w4[c*64 + lane], x = v4[c*64 + lane];
    s += w.x*x.x + w.y*x.y + w.z*x.z + w.w*x.w;
  }
  if (lane < 32) {
    float4 w = w4[128 + lane], x = v4[128 + lane];
    s += w.x*x.x + w.y*x.y + w.z*x.z + w.w*x.w;
  }
  return s;
}

// ---- barriers: per-wave vmcnt drain + flag store; detector broadcasts ----
// worker arrival (wait optional; data visibility via sc-flagged write-through stores)
__device__ __forceinline__ void wbar(unsigned* bar, int bid, unsigned n, bool wait) {
  asm volatile("s_waitcnt vmcnt(0)" ::: "memory");
  __syncthreads();
  if (threadIdx.x == 0) {
    astore(bar + bid*4, n);
    if (wait) {
      const unsigned* lg = bar + LGEN_OFF + (bid/GRPSZ)*64;
      while (aload(lg) < n) __builtin_amdgcn_s_sleep(2);
    }
  }
  __syncthreads();
}
// detector: arrive, poll all flags in parallel, broadcast to 32 lgen lines
__device__ __forceinline__ void dbar(unsigned* bar, unsigned n) {
  asm volatile("s_waitcnt vmcnt(0)" ::: "memory");
  __syncthreads();
  const int tid = threadIdx.x;
  if (tid == 0) astore(bar + DET*4, n);
  {
    const unsigned* fl = bar + tid*4;          // tid < GBK == NT
    while (aload(fl) < n) __builtin_amdgcn_s_sleep(1);
  }
  __syncthreads();
  if (tid < NGRP) astore(bar + LGEN_OFF + tid*64, n);
  __syncthreads();
}
// gang barrier: 16 blocks, all-to-all flags
__device__ __forceinline__ void gbar(unsigned* bar, int gi, unsigned m) {
  asm volatile("s_waitcnt vmcnt(0)" ::: "memory");
  __syncthreads();
  if (threadIdx.x == 0) astore(bar + GFLG_OFF + gi*4, m);
  if (threadIdx.x < 16) {
    const unsigned* fl = bar + GFLG_OFF + threadIdx.x*4;
    while (aload(fl) < m) __builtin_amdgcn_s_sleep(1);
  }
  __syncthreads();
}

// ---------- prep kernels ----------
__global__ void conv_bf16(const float* __restrict__ src, ushortT* __restrict__ dst, size_t n) {
  size_t i  = blockIdx.x * (size_t)blockDim.x + threadIdx.x;
  size_t st = (size_t)gridDim.x * blockDim.x;
  for (; i < n; i += st) dst[i] = f2bf(src[i]);
}

__global__ void prep_kv(const float* __restrict__ text, const float* __restrict__ Wk,
                        const float* __restrict__ Wv, ushortT* __restrict__ keys,
                        ushortT* __restrict__ vals) {
  __shared__ float tx[ATT];
  const int t = blockIdx.x;
  for (int i = threadIdx.x; i < ATT; i += blockDim.x) tx[i] = text[(size_t)t*ATT + i];
  __syncthreads();
  for (int a = threadIdx.x; a < 2*ATT; a += blockDim.x) {
    const int which = (a >= ATT);
    const int ar = a - which*ATT;
    const float4* w4 = (const float4*)((which ? Wv : Wk) + (size_t)ar*ATT);
    const float4* t4 = (const float4*)tx;
    float s = 0.f;
    for (int i = 0; i < ATT/4; ++i) {
      float4 w = w4[i], x = t4[i];
      s += w.x*x.x + w.y*x.y + w.z*x.z + w.w*x.w;
    }
    (which ? vals : keys)[(size_t)t*ATT + ar] = f2bf(s);
  }
}

__global__ void prep_zero(float* f, unsigned* bar) {
  int i = blockIdx.x * blockDim.x + threadIdx.x;
  if (i < F_END) f[i] = 0.f;
  if (i < BAR_N) bar[i] = 0u;
}

// ---------- persistent AR kernel ----------
__global__ void __launch_bounds__(NT, 4)
ar_persist(const float* __restrict__ residual,
           const float* __restrict__ Whh_a, const float* __restrict__ Whh0g,
           const float* __restrict__ Wih1g,
           const float* __restrict__ b_a, const float* __restrict__ v_attn,
           const float* __restrict__ b0, const float* __restrict__ b1,
           const float* __restrict__ bd1, const float* __restrict__ bd2,
           const float* __restrict__ Wc, const float* __restrict__ bc,
           const float* __restrict__ Wg, const float* __restrict__ bg,
           float* __restrict__ out, void* __restrict__ wsraw)
{
  const int tid  = threadIdx.x;
  const int bid  = blockIdx.x;
  const int wid  = tid >> 6;     // 8 waves
  const int lane = tid & 63;

  const ushortT* uws = (const ushortT*)wsraw;
  float*    f   = (float*)((char*)wsraw + FBYTE);
  unsigned* bar = (unsigned*)((char*)wsraw + BBYTE);

  const ushortT* wq    = uws + O_WQ;
  const ushortT* wiha  = uws + O_WIHA;
  const ushortT* wih0  = uws + O_WIH0;
  const ushortT* whh1s = uws + O_WHH1;
  const ushortT* wd1   = uws + O_WD1;
  const ushortT* wd2   = uws + O_WD2;
  const ushortT* keys  = uws + O_KEYS;
  const ushortT* vals  = uws + O_VALS;

  const bool isDet  = (bid == DET);
  const bool isGang = (bid < 16);
  const bool isAttn = (bid >= ATT_B0 && bid < ATT_B0 + NATT);

  // this block: hidden units {2*bid, 2*bid+1}; wave wid -> gate gi4 of hidden hj
  const int hj = wid >> 2, gi4 = wid & 3;
  const int zrow = gi4*H + bid*2 + hj;          // row of the 4H-dim z

  __shared__ ushortT lWhha[8*H];    // 16 KB each
  __shared__ ushortT lWih0H[8*H];
  __shared__ ushortT lWhh0[8*H];
  __shared__ ushortT lWih1[8*H];
  __shared__ float   shv[2048];
  __shared__ float   lctx[ATT];
  __shared__ float   zl[8], zp[8], sc[64], cells[6], misc2[4], sAZ[4];

  // ---- stage this block's recurrent rows into LDS ----
  {
    us4* dA = (us4*)lWhha;  us4* dB = (us4*)lWih0H;
    us4* dC = (us4*)lWhh0;  us4* dD = (us4*)lWih1;
    const us4* s0 = (const us4*)wih0;
    #pragma unroll
    for (int c = 0; c < 4; ++c) {
      const int ei = c*64 + lane;
      dA[wid*256 + ei] = cvt4(*(const float4*)(Whh_a + (size_t)zrow*H + ei*4));
      dC[wid*256 + ei] = cvt4(*(const float4*)(Whh0g + (size_t)zrow*H + ei*4));
      dD[wid*256 + ei] = cvt4(*(const float4*)(Wih1g + (size_t)zrow*H + ei*4));
      dB[wid*256 + ei] = s0[(size_t)zrow*416 + ei];
    }
  }
  if (tid < 6) cells[tid] = 0.f;
  __syncthreads();

  int pa = 0, p1 = 0;
  unsigned nb = 0;   // main barrier epoch
  unsigned mg = 0;   // gang barrier epoch

  for (int s = 0; s < T_STEPS; ++s) {
    // ===== W1: z_a = Wih_a@x + Whh_a@ha + b_a -> ha, ca =====
    cstage(shv, f + F_X, 80);
    cstage(shv + 128, f + F_HA + pa*H, H);
    __syncthreads();
    {
      float s1 = 0.f;
      if (lane < 20) {
        us4 w = ((const us4*)wiha)[(size_t)zrow*20 + lane];
        float4 xv = ((const float4*)shv)[lane];
        s1 = bf2f(w[0])*xv.x + bf2f(w[1])*xv.y + bf2f(w[2])*xv.z + bf2f(w[3])*xv.w;
      }
      s1 += dotbf(lWhha + wid*H, shv + 128, lane);
      s1 = red64(s1) + b_a[zrow];
      if (lane == 0) zl[wid] = s1;
    }
    __syncthreads();
    if (tid < 2) {
      float iv = zl[tid*4+0], fv = zl[tid*4+1], gv = zl[tid*4+2], ov = zl[tid*4+3];
      float c = sigf(fv)*cells[tid] + sigf(iv)*tanhf(gv);
      float h = sigf(ov)*tanhf(c);
      cells[tid] = c;
      cstore(f + F_HA + (pa^1)*H + bid*2 + tid, h);
    }
    pa ^= 1;
    ++nb;                                     // ---- A: ha ready (all wait)
    if (isDet) dbar(bar, nb); else wbar(bar, bid, nb, true);

    // ===== W2: z0part (local) ; q rows ; gate_ha =====
    cstage(shv, f + F_HA + pa*H, H);
    cstage(shv + 1024, f + F_H0, H);
    __syncthreads();
    {
      float s2 = dotbf(lWih0H + wid*H, shv, lane)
               + dotbf(lWhh0 + wid*H, shv + 1024, lane);
      s2 = red64(s2) + b0[zrow];
      if (lane == 0) zp[wid] = s2;
      if (wid == 0) {                         // q row bid
        float sq = dotbf(wq + (size_t)bid*H, shv, lane);
        sq = red64(sq);
        if (lane == 0) cstore(f + F_Q + bid, sq);
      }
      if (wid == 1 && bid < ATT - GBK) {      // q rows 512..639
        const int qr = GBK + bid;
        float sq = dotbf(wq + (size_t)qr*H, shv, lane);
        sq = red64(sq);
        if (lane == 0) cstore(f + F_Q + qr, sq);
      }
      if (bid == GATE_B && wid == 2) {        // gate ha-part (fp32 Wg)
        float sg = dotf(Wg, shv, lane);
        sg = red64(sg);
        if (lane == 0) misc2[0] = sg;
      }
    }
    ++nb;                                     // ---- B: q ready (only attn waits)
    if (isDet) dbar(bar, nb); else wbar(bar, bid, nb, isAttn);

    // ===== W3: attention (4 blocks x 50 positions, no-max exp) =====
    if (isAttn) {
      const int ab = bid - ATT_B0;
      const int t0 = ab * 50;
      cstage(shv, f + F_Q, ATT);
      __syncthreads();
      for (int pl = wid; pl < 50; pl += 8) {
        const int t = t0 + pl;
        float ss = 0.f;
        #pragma unroll
        for (int i = 0; i < 10; ++i) {
          const int idx = lane + 64*i;
          ss += tanhf(bf2f(keys[(size_t)t*ATT + idx]) + shv[idx]) * v_attn[idx];
        }
        ss = red64(ss);
        if (lane == 0) sc[pl] = expf(ss);     // |ss| <= sum|v_attn| ~ 10 -> safe
      }
      __syncthreads();
      if (tid == 0) {
        float z = 0.f;
        for (int i = 0; i < 50; ++i) z += sc[i];
        cstore(f + F_AZ4 + ab, z);
      }
      for (int a = tid; a < ATT; a += NT) {
        float acc = 0.f;
        for (int i = 0; i < 50; ++i)
          acc += sc[i] * bf2f(vals[(size_t)(t0 + i)*ATT + a]);
        cstore(f + F_CP4 + ab*ATT + a, acc);
      }
    }
    ++nb;                                     // ---- C: ctx partials ready (all wait)
    if (isDet) dbar(bar, nb); else wbar(bar, bid, nb, true);

    // ===== W4: combine 4 partials -> lctx ; z0 finish -> h0 ; gate out =====
    if (tid < 4) sAZ[tid] = cload(f + F_AZ4 + tid);
    __syncthreads();
    {
      const float inv = 1.0f / (sAZ[0] + sAZ[1] + sAZ[2] + sAZ[3]);
      for (int a = tid; a < ATT; a += NT) {
        float c = cload(f + F_CP4 + a)        + cload(f + F_CP4 + ATT + a)
                + cload(f + F_CP4 + 2*ATT + a) + cload(f + F_CP4 + 3*ATT + a);
        lctx[a] = c * inv;
      }
    }
    __syncthreads();
    {
      float s4 = dot640bf(wih0 + (size_t)zrow*DIN + H, lctx, lane);
      s4 = red64(s4) + zp[wid];
      if (lane == 0) zl[wid] = s4;
    }
    __syncthreads();
    if (tid < 2) {
      float iv = zl[tid*4+0], fv = zl[tid*4+1], gv = zl[tid*4+2], ov = zl[tid*4+3];
      float c = sigf(fv)*cells[2+tid] + sigf(iv)*tanhf(gv);
      float h = sigf(ov)*tanhf(c);
      cells[2+tid] = c;
      cstore(f + F_H0 + bid*2 + tid, h);
    }
    if (bid == GATE_B && wid == 3) {
      float sg = dot640f(Wg + H, lctx, lane);
      sg = red64(sg);
      if (lane == 0) out[T_STEPS*NMEL + s] = sigf(sg + misc2[0] + bg[0]);
    }
    ++nb;                                     // ---- D: h0 ready (all wait)
    if (isDet) dbar(bar, nb); else wbar(bar, bid, nb, true);

    // ===== W5: z1 = Wih1@h0 + Whh1@h1 + b1 -> h1 =====
    cstage(shv, f + F_H0, H);
    cstage(shv + 1024, f + F_H1 + p1*H, H);
    __syncthreads();
    {
      float s5 = dotbf(lWih1 + wid*H, shv, lane)
               + dotbf(whh1s + (size_t)zrow*H, shv + 1024, lane);
      s5 = red64(s5) + b1[zrow];
      if (lane == 0) zl[wid] = s5;
    }
    __syncthreads();
    if (tid < 2) {
      float iv = zl[tid*4+0], fv = zl[tid*4+1], gv = zl[tid*4+2], ov = zl[tid*4+3];
      float c = sigf(fv)*cells[4+tid] + sigf(iv)*tanhf(gv);
      float h = sigf(ov)*tanhf(c);
      cells[4+tid] = c;
      cstore(f + F_H1 + (p1^1)*H + bid*2 + tid, h);
    }
    p1 ^= 1;
    ++nb;                                     // ---- E: h1 ready (only gang waits)
    if (isDet) dbar(bar, nb); else wbar(bar, bid, nb, isGang);

    // ===== W6-W8: decoder gang (blocks 0..15) =====
    if (isGang) {
      // W6: d1 = tanh(Wd1@h1 + bd1), 64 rows per block
      cstage(shv, f + F_H1 + p1*H, H);
      __syncthreads();
      for (int r8 = 0; r8 < 8; ++r8) {
        const int r = bid*64 + wid*8 + r8;
        float s6 = dotbf(wd1 + (size_t)r*H, shv, lane);
        s6 = red64(s6);
        if (lane == 0) cstore(f + F_D1 + r, tanhf(s6 + bd1[r]));
      }
      gbar(bar, bid, ++mg);
      // W7: d = tanh(Wd2@d1 + bd2)
      cstage(shv, f + F_D1, H);
      __syncthreads();
      for (int r8 = 0; r8 < 8; ++r8) {
        const int r = bid*64 + wid*8 + r8;
        float s7 = dotbf(wd2 + (size_t)r*H, shv, lane);
        s7 = red64(s7);
        if (lane == 0) cstore(f + F_D + r, tanhf(s7 + bd2[r]));
      }
      gbar(bar, bid, ++mg);
      // W8: dec_out rows, out, next x (5 mels per block)
      cstage(shv, f + F_D, H);
      __syncthreads();
      if (wid < 5) {
        const int mel = bid*5 + wid;
        float sl = dotf(Wc + (size_t)mel*H, shv, lane);
        sl = red64(sl);
        float sb = dotf(Wc + (size_t)(NMEL + mel)*H, shv, lane);
        sb = red64(sb);
        if (lane == 0) {
          const int idx = T_STEPS - 1 - s;
          const float r = residual[idx*NMEL + mel];
          const float o = (r - (sb + bc[NMEL + mel])) * expf(-(sl + bc[mel]));
          out[idx*NMEL + mel] = o;
          cstore(f + F_X + mel, o);
        }
      }
    } else {
      mg += 2;
    }
    ++nb;                                     // ---- F: x ready (all wait)
    if (isDet) dbar(bar, nb); else wbar(bar, bid, nb, true);
  }
}

extern "C" void kernel_launch(void* const* d_in, const int* in_sizes, int n_in,
                              void* d_out, int out_size, void* d_ws, size_t ws_size,
                              hipStream_t stream) {
  const float* residual = (const float*)d_in[0];
  const float* text   = (const float*)d_in[1];
  const float* Wih_a  = (const float*)d_in[2];
  const float* Whh_a  = (const float*)d_in[3];
  const float* b_a    = (const float*)d_in[4];
  const float* Wq     = (const float*)d_in[5];
  const float* Wk     = (const float*)d_in[6];
  const float* Wv     = (const float*)d_in[7];
  const float* v_attn = (const float*)d_in[8];
  const float* Wih0   = (const float*)d_in[9];
  const float* Whh0   = (const float*)d_in[10];
  const float* b0     = (const float*)d_in[11];
  const float* Wih1   = (const float*)d_in[12];
  const float* Whh1   = (const float*)d_in[13];
  const float* b1     = (const float*)d_in[14];
  const float* Wd1    = (const float*)d_in[15];
  const float* bd1    = (const float*)d_in[16];
  const float* Wd2    = (const float*)d_in[17];
  const float* bd2    = (const float*)d_in[18];
  const float* Wc     = (const float*)d_in[19];
  const float* bc     = (const float*)d_in[20];
  const float* Wg     = (const float*)d_in[21];
  const float* bg     = (const float*)d_in[22];
  float* out = (float*)d_out;

  char* wsb = (char*)d_ws;
  ushortT*  u   = (ushortT*)wsb;
  float*    f   = (float*)(wsb + FBYTE);
  unsigned* bar = (unsigned*)(wsb + BBYTE);

  conv_bf16<<<1024, 256, 0, stream>>>(Wq,    u + O_WQ,   (size_t)ATT*H);
  conv_bf16<<<1024, 256, 0, stream>>>(Wih_a, u + O_WIHA, (size_t)4*H*NMEL);
  conv_bf16<<<1024, 256, 0, stream>>>(Wih0,  u + O_WIH0, (size_t)4*H*DIN);
  conv_bf16<<<1024, 256, 0, stream>>>(Whh1,  u + O_WHH1, (size_t)4*H*H);
  conv_bf16<<<1024, 256, 0, stream>>>(Wd1,   u + O_WD1,  (size_t)H*H);
  conv_bf16<<<1024, 256, 0, stream>>>(Wd2,   u + O_WD2,  (size_t)H*H);
  prep_kv<<<TXT, 256, 0, stream>>>(text, Wk, Wv, u + O_KEYS, u + O_VALS);
  prep_zero<<<64, 256, 0, stream>>>(f, bar);

  ar_persist<<<GBK, NT, 0, stream>>>(residual, Whh_a, Whh0, Wih1,
      b_a, v_attn, b0, b1, bd1, bd2, Wc, bc, Wg, bg, out, d_ws);
}

// Round 7
// 27135.880 us; speedup vs baseline: 1.9270x; 1.9270x over previous
//
#include <hip/hip_runtime.h>
#include <hip/hip_bf16.h>
#include <math.h>

#define GBK 256          // grid blocks (1 per CU, co-resident: LDS > 80KB)
#define NT  512          // threads per block (8 waves)

constexpr int T_STEPS = 600;
constexpr int TXT     = 200;
constexpr int NMEL    = 80;
constexpr int H       = 1024;
constexpr int ATT     = 640;
constexpr int DIN     = H + ATT;   // 1664
constexpr int ATT_B0  = 128;       // attention blocks 128..135
constexpr int NATT    = 8;
constexpr int GATE_B  = 200;       // gate-output block
constexpr int FSTR    = 32;        // uints per barrier flag line (128B)

// ---- ws layout: bf16 region (ushort element offsets) ----
constexpr size_t O_WQ    = 0;                                  // 640*1024
constexpr size_t O_WIHA  = O_WQ   + (size_t)ATT*H;             // 4096*80
constexpr size_t O_WIH0  = O_WIHA + (size_t)4*H*NMEL;          // 4096*1664
constexpr size_t O_WHH1  = O_WIH0 + (size_t)4*H*DIN;           // 4096*1024
constexpr size_t O_WD1   = O_WHH1 + (size_t)4*H*H;             // 1024*1024
constexpr size_t O_WD2   = O_WD1  + (size_t)H*H;
constexpr size_t O_KEYS  = O_WD2  + (size_t)H*H;               // 200*640
constexpr size_t O_VALS  = O_KEYS + (size_t)TXT*ATT;
constexpr size_t O_END_U = O_VALS + (size_t)TXT*ATT;
constexpr size_t FBYTE   = ((O_END_U*2 + 255)/256)*256;        // float region start
// ---- float region (float element offsets) ----
constexpr int F_X   = 0;             // 128 (80 used)
constexpr int F_HA  = 128;           // 2*H ping-pong
constexpr int F_H0  = F_HA + 2*H;    // H
constexpr int F_H1  = F_H0 + H;      // 2*H ping-pong
constexpr int F_Q   = F_H1 + 2*H;    // ATT
constexpr int F_D1  = F_Q  + ATT;    // H
constexpr int F_D   = F_D1 + H;      // H
constexpr int F_AZ  = F_D  + H;      // 16 (8 used: partial sum-exp)
constexpr int F_CP  = F_AZ + 16;     // 8*ATT unnormalized ctx partials
constexpr int F_END = F_CP + NATT*ATT;
constexpr size_t BBYTE  = FBYTE + (((size_t)F_END*4 + 255)/256)*256;
constexpr int BAR_N = GBK*FSTR;      // 8192 uints

typedef unsigned short ushortT;
typedef ushortT us4 __attribute__((ext_vector_type(4)));

__device__ __forceinline__ float bf2f(ushortT u) {
  return __uint_as_float(((unsigned)u) << 16);
}
__device__ __forceinline__ ushortT f2bf(float x) {
  __hip_bfloat16 h = __float2bfloat16(x);
  ushortT u; __builtin_memcpy(&u, &h, 2); return u;
}
__device__ __forceinline__ us4 cvt4(float4 a) {
  return us4{ f2bf(a.x), f2bf(a.y), f2bf(a.z), f2bf(a.w) };
}
__device__ __forceinline__ float sigf(float x) { return 1.0f / (1.0f + expf(-x)); }

__device__ __forceinline__ float red64(float v) {
  #pragma unroll
  for (int off = 32; off > 0; off >>= 1) v += __shfl_xor(v, off, 64);
  return v;
}

// coherent (agent-scope, cache-bypassing) accessors for dynamic cross-block data
__device__ __forceinline__ float cload(const float* p) {
  return __hip_atomic_load(p, __ATOMIC_RELAXED, __HIP_MEMORY_SCOPE_AGENT);
}
__device__ __forceinline__ void cstore(float* p, float v) {
  __hip_atomic_store(p, v, __ATOMIC_RELAXED, __HIP_MEMORY_SCOPE_AGENT);
}
__device__ __forceinline__ void cstage(float* dst, const float* src, int n) {
  for (int i = threadIdx.x; i < n; i += NT) dst[i] = cload(src + i);
}
__device__ __forceinline__ unsigned aload(const unsigned* p) {
  return __hip_atomic_load(p, __ATOMIC_RELAXED, __HIP_MEMORY_SCOPE_AGENT);
}
__device__ __forceinline__ void astore(unsigned* p, unsigned v) {
  __hip_atomic_store(p, v, __ATOMIC_RELAXED, __HIP_MEMORY_SCOPE_AGENT);
}

// ---- conflict-free dots: lane handles float4/us4 index c*64+lane ----
__device__ __forceinline__ float dotbf(const ushortT* __restrict__ Wrow,
                                       const float* __restrict__ v, int lane) {
  const us4* w4 = (const us4*)Wrow;
  const float4* v4 = (const float4*)v;
  float s = 0.f;
  #pragma unroll
  for (int c = 0; c < 4; ++c) {
    us4 w = w4[c*64 + lane];
    float4 x = v4[c*64 + lane];
    s += bf2f(w[0])*x.x + bf2f(w[1])*x.y + bf2f(w[2])*x.z + bf2f(w[3])*x.w;
  }
  return s;
}
__device__ __forceinline__ float dot640bf(const ushortT* __restrict__ Wrow,
                                          const float* __restrict__ v, int lane) {
  const us4* w4 = (const us4*)Wrow;
  const float4* v4 = (const float4*)v;
  float s = 0.f;
  #pragma unroll
  for (int c = 0; c < 2; ++c) {
    us4 w = w4[c*64 + lane];
    float4 x = v4[c*64 + lane];
    s += bf2f(w[0])*x.x + bf2f(w[1])*x.y + bf2f(w[2])*x.z + bf2f(w[3])*x.w;
  }
  if (lane < 32) {
    us4 w = w4[128 + lane];
    float4 x = v4[128 + lane];
    s += bf2f(w[0])*x.x + bf2f(w[1])*x.y + bf2f(w[2])*x.z + bf2f(w[3])*x.w;
  }
  return s;
}
__device__ __forceinline__ float dotf(const float* __restrict__ Wrow,
                                      const float* __restrict__ v, int lane) {
  const float4* w4 = (const float4*)Wrow;
  const float4* v4 = (const float4*)v;
  float s = 0.f;
  #pragma unroll
  for (int c = 0; c < 4; ++c) {
    float4 w = w4[c*64 + lane], x = v4[c*64 + lane];
    s += w.x*x.x + w.y*x.y + w.z*x.z + w.w*x.w;
  }
  return s;
}
__device__ __forceinline__ float dot640f(const float* __restrict__ Wrow,
                                         const float* __restrict__ v, int lane) {
  const float4* w4 = (const float4*)Wrow;
  const float4* v4 = (const float4*)v;
  float s = 0.f;
  #pragma unroll
  for (int c = 0; c < 2; ++c) {
    float4 w = w4[c*64 + lane], x = v4[c*64 + lane];
    s += w.x*x.x + w.y*x.y + w.z*x.z + w.w*x.w;
  }
  if (lane < 32) {
    float4 w = w4[128 + lane], x = v4[128 + lane];
    s += w.x*x.x + w.y*x.y + w.z*x.z + w.w*x.w;
  }
  return s;
}

// single-hop all-to-all grid barrier: own-flag store (no contention),
// wave 0's 64 lanes poll 4 flags each in parallel. Monotonic epochs.
__device__ __forceinline__ void abar(unsigned* bar, int bid, unsigned n) {
  asm volatile("s_waitcnt vmcnt(0)" ::: "memory");
  __syncthreads();
  const int tid = threadIdx.x;
  if (tid == 0) astore(bar + bid*FSTR, n);
  if (tid < 64) {
    const unsigned* p0 = bar + (tid*4 + 0)*FSTR;
    const unsigned* p1 = bar + (tid*4 + 1)*FSTR;
    const unsigned* p2 = bar + (tid*4 + 2)*FSTR;
    const unsigned* p3 = bar + (tid*4 + 3)*FSTR;
    while (true) {
      unsigned a = aload(p0), b = aload(p1), c = aload(p2), d = aload(p3);
      unsigned m = a < b ? a : b;
      unsigned m2 = c < d ? c : d;
      m = m < m2 ? m : m2;
      if (m >= n) break;
      __builtin_amdgcn_s_sleep(1);
    }
  }
  __syncthreads();
}

// ---------- prep kernels ----------
__global__ void conv_bf16(const float* __restrict__ src, ushortT* __restrict__ dst, size_t n) {
  size_t i  = blockIdx.x * (size_t)blockDim.x + threadIdx.x;
  size_t st = (size_t)gridDim.x * blockDim.x;
  for (; i < n; i += st) dst[i] = f2bf(src[i]);
}

__global__ void prep_kv(const float* __restrict__ text, const float* __restrict__ Wk,
                        const float* __restrict__ Wv, ushortT* __restrict__ keys,
                        ushortT* __restrict__ vals) {
  __shared__ float tx[ATT];
  const int t = blockIdx.x;
  for (int i = threadIdx.x; i < ATT; i += blockDim.x) tx[i] = text[(size_t)t*ATT + i];
  __syncthreads();
  for (int a = threadIdx.x; a < 2*ATT; a += blockDim.x) {
    const int which = (a >= ATT);
    const int ar = a - which*ATT;
    const float4* w4 = (const float4*)((which ? Wv : Wk) + (size_t)ar*ATT);
    const float4* t4 = (const float4*)tx;
    float s = 0.f;
    for (int i = 0; i < ATT/4; ++i) {
      float4 w = w4[i], x = t4[i];
      s += w.x*x.x + w.y*x.y + w.z*x.z + w.w*x.w;
    }
    (which ? vals : keys)[(size_t)t*ATT + ar] = f2bf(s);
  }
}

__global__ void prep_zero(float* f, unsigned* bar) {
  int i = blockIdx.x * blockDim.x + threadIdx.x;
  if (i < F_END) f[i] = 0.f;
  if (i < BAR_N) bar[i] = 0u;
}

// ---------- persistent AR kernel ----------
__global__ void __launch_bounds__(NT, 1)
ar_persist(const float* __restrict__ residual,
           const float* __restrict__ Whh_a, const float* __restrict__ Whh0g,
           const float* __restrict__ Wih1g,
           const float* __restrict__ b_a, const float* __restrict__ v_attn,
           const float* __restrict__ b0, const float* __restrict__ b1,
           const float* __restrict__ bd1, const float* __restrict__ bd2,
           const float* __restrict__ Wc, const float* __restrict__ bc,
           const float* __restrict__ Wg, const float* __restrict__ bg,
           float* __restrict__ out, void* __restrict__ wsraw)
{
  const int tid  = threadIdx.x;
  const int bid  = blockIdx.x;
  const int wid  = tid >> 6;     // 8 waves
  const int lane = tid & 63;

  const ushortT* uws = (const ushortT*)wsraw;
  float*    f   = (float*)((char*)wsraw + FBYTE);
  unsigned* bar = (unsigned*)((char*)wsraw + BBYTE);

  const ushortT* wq    = uws + O_WQ;
  const ushortT* wiha  = uws + O_WIHA;
  const ushortT* wih0s = uws + O_WIH0;
  const ushortT* whh1s = uws + O_WHH1;
  const ushortT* wd1   = uws + O_WD1;
  const ushortT* wd2   = uws + O_WD2;
  const ushortT* keys  = uws + O_KEYS;
  const ushortT* vals  = uws + O_VALS;

  const bool isAttn = (bid >= ATT_B0 && bid < ATT_B0 + NATT);

  // block owns units [bid*4, bid*4+4); 16 z-rows; wave wid -> row_locals 2w, 2w+1
  // row_local rl: gate = rl>>2, unit = rl&3 ; zrow = gate*H + bid*4 + unit
  const int ub = bid*4;
  const int rlA = wid*2, rlB = wid*2 + 1;
  const int zrA = (rlA>>2)*H + ub + (rlA&3);
  const int zrB = (rlB>>2)*H + ub + (rlB&3);

  __shared__ ushortT lWhha[16*H];   // 32 KB each
  __shared__ ushortT lWhh0[16*H];
  __shared__ ushortT lWih1[16*H];
  __shared__ float   shv[2048];
  __shared__ float   lctx[ATT];
  __shared__ float   zl[16], zp[16], sc[32], misc2[4], sAZ[8];
  __shared__ float   cA[4], c0S[4], c1S[4];

  // ---- stage this block's recurrent rows into LDS (bf16, us4 layout) ----
  {
    us4* dA = (us4*)lWhha; us4* dC = (us4*)lWhh0; us4* dD = (us4*)lWih1;
    #pragma unroll
    for (int j = 0; j < 2; ++j) {
      const int rl = wid*2 + j;
      const int zr = (rl>>2)*H + ub + (rl&3);
      #pragma unroll
      for (int c = 0; c < 4; ++c) {
        const int ei = c*64 + lane;
        dA[rl*256 + ei] = cvt4(*(const float4*)(Whh_a + (size_t)zr*H + ei*4));
        dC[rl*256 + ei] = cvt4(*(const float4*)(Whh0g + (size_t)zr*H + ei*4));
        dD[rl*256 + ei] = cvt4(*(const float4*)(Wih1g + (size_t)zr*H + ei*4));
      }
    }
  }
  if (tid < 4) { cA[tid] = 0.f; c0S[tid] = 0.f; c1S[tid] = 0.f; }
  __syncthreads();

  int pa = 0, p1 = 0;
  unsigned nb = 0;

  for (int s = 0; s < T_STEPS; ++s) {
    // ===== P1: z_a = Wih_a@x + Whh_a@ha + b_a -> ha, ca =====
    cstage(shv, f + F_X, 80);
    cstage(shv + 128, f + F_HA + pa*H, H);
    __syncthreads();
    {
      float sA = 0.f, sB = 0.f;
      if (lane < 20) {
        float4 xv = ((const float4*)shv)[lane];
        us4 w = ((const us4*)wiha)[(size_t)zrA*20 + lane];
        sA = bf2f(w[0])*xv.x + bf2f(w[1])*xv.y + bf2f(w[2])*xv.z + bf2f(w[3])*xv.w;
        w = ((const us4*)wiha)[(size_t)zrB*20 + lane];
        sB = bf2f(w[0])*xv.x + bf2f(w[1])*xv.y + bf2f(w[2])*xv.z + bf2f(w[3])*xv.w;
      }
      sA += dotbf(lWhha + rlA*H, shv + 128, lane);
      sB += dotbf(lWhha + rlB*H, shv + 128, lane);
      sA = red64(sA) + b_a[zrA];
      sB = red64(sB) + b_a[zrB];
      if (lane == 0) { zl[rlA] = sA; zl[rlB] = sB; }
    }
    __syncthreads();
    if (tid < 4) {
      float iv = zl[tid], fv = zl[4+tid], gv = zl[8+tid], ov = zl[12+tid];
      float c = sigf(fv)*cA[tid] + sigf(iv)*tanhf(gv);
      float h = sigf(ov)*tanhf(c);
      cA[tid] = c;
      cstore(f + F_HA + (pa^1)*H + ub + tid, h);
    }
    pa ^= 1;
    abar(bar, bid, ++nb);                         // A: ha ready

    // ===== P2: z0part = Wih0[:,:H]@ha + Whh0@h0 + b0 ; q rows ; gate_ha =====
    cstage(shv, f + F_HA + pa*H, H);
    cstage(shv + 1024, f + F_H0, H);
    __syncthreads();
    {
      float sA = dotbf(wih0s + (size_t)zrA*DIN, shv, lane)
               + dotbf(lWhh0 + rlA*H, shv + 1024, lane);
      float sB = dotbf(wih0s + (size_t)zrB*DIN, shv, lane)
               + dotbf(lWhh0 + rlB*H, shv + 1024, lane);
      sA = red64(sA) + b0[zrA];
      sB = red64(sB) + b0[zrB];
      if (lane == 0) { zp[rlA] = sA; zp[rlB] = sB; }
      if (wid < 3) {                              // up to 3 q rows per block
        const int qr = bid + wid*GBK;
        if (qr < ATT) {
          float sq = dotbf(wq + (size_t)qr*H, shv, lane);
          sq = red64(sq);
          if (lane == 0) cstore(f + F_Q + qr, sq);
        }
      }
      if (bid == GATE_B && wid == 3) {            // gate ha-part (fp32 Wg)
        float sg = dotf(Wg, shv, lane);
        sg = red64(sg);
        if (lane == 0) misc2[0] = sg;
      }
    }
    abar(bar, bid, ++nb);                         // B: q ready

    // ===== P3: attention (8 blocks x 25 positions, no-max exp) =====
    if (isAttn) {
      const int ab = bid - ATT_B0;
      const int t0 = ab * 25;
      cstage(shv, f + F_Q, ATT);
      __syncthreads();
      for (int pl = wid; pl < 25; pl += 8) {
        const int t = t0 + pl;
        float ss = 0.f;
        #pragma unroll
        for (int i = 0; i < 10; ++i) {
          const int idx = lane + 64*i;
          ss += tanhf(bf2f(keys[(size_t)t*ATT + idx]) + shv[idx]) * v_attn[idx];
        }
        ss = red64(ss);
        if (lane == 0) sc[pl] = expf(ss);         // |ss| small -> safe without max
      }
      __syncthreads();
      if (tid == 0) {
        float z = 0.f;
        for (int i = 0; i < 25; ++i) z += sc[i];
        cstore(f + F_AZ + ab, z);
      }
      for (int a = tid; a < ATT; a += NT) {
        float acc = 0.f;
        for (int i = 0; i < 25; ++i)
          acc += sc[i] * bf2f(vals[(size_t)(t0 + i)*ATT + a]);
        cstore(f + F_CP + ab*ATT + a, acc);
      }
    }
    abar(bar, bid, ++nb);                         // C: ctx partials ready

    // ===== P4: combine partials -> lctx ; z0 finish -> h0 ; gate out =====
    if (tid < 8) sAZ[tid] = cload(f + F_AZ + tid);
    __syncthreads();
    {
      float Zt = 0.f;
      #pragma unroll
      for (int i = 0; i < 8; ++i) Zt += sAZ[i];
      const float inv = 1.0f / Zt;
      for (int a = tid; a < ATT; a += NT) {
        float c = 0.f;
        #pragma unroll
        for (int p = 0; p < 8; ++p) c += cload(f + F_CP + p*ATT + a);
        lctx[a] = c * inv;
      }
    }
    __syncthreads();
    {
      float sA = dot640bf(wih0s + (size_t)zrA*DIN + H, lctx, lane);
      float sB = dot640bf(wih0s + (size_t)zrB*DIN + H, lctx, lane);
      sA = red64(sA) + zp[rlA];
      sB = red64(sB) + zp[rlB];
      if (lane == 0) { zl[rlA] = sA; zl[rlB] = sB; }
    }
    __syncthreads();
    if (tid < 4) {
      float iv = zl[tid], fv = zl[4+tid], gv = zl[8+tid], ov = zl[12+tid];
      float c = sigf(fv)*c0S[tid] + sigf(iv)*tanhf(gv);
      float h = sigf(ov)*tanhf(c);
      c0S[tid] = c;
      cstore(f + F_H0 + ub + tid, h);
    }
    if (bid == GATE_B && wid == 3) {
      float sg = dot640f(Wg + H, lctx, lane);
      sg = red64(sg);
      if (lane == 0) out[T_STEPS*NMEL + s] = sigf(sg + misc2[0] + bg[0]);
    }
    abar(bar, bid, ++nb);                         // D: h0 ready

    // ===== P5: z1 = Wih1@h0 + Whh1@h1 + b1 -> h1 =====
    cstage(shv, f + F_H0, H);
    cstage(shv + 1024, f + F_H1 + p1*H, H);
    __syncthreads();
    {
      float sA = dotbf(lWih1 + rlA*H, shv, lane)
               + dotbf(whh1s + (size_t)zrA*H, shv + 1024, lane);
      float sB = dotbf(lWih1 + rlB*H, shv, lane)
               + dotbf(whh1s + (size_t)zrB*H, shv + 1024, lane);
      sA = red64(sA) + b1[zrA];
      sB = red64(sB) + b1[zrB];
      if (lane == 0) { zl[rlA] = sA; zl[rlB] = sB; }
    }
    __syncthreads();
    if (tid < 4) {
      float iv = zl[tid], fv = zl[4+tid], gv = zl[8+tid], ov = zl[12+tid];
      float c = sigf(fv)*c1S[tid] + sigf(iv)*tanhf(gv);
      float h = sigf(ov)*tanhf(c);
      c1S[tid] = c;
      cstore(f + F_H1 + (p1^1)*H + ub + tid, h);
    }
    p1 ^= 1;
    abar(bar, bid, ++nb);                         // E: h1 ready

    // ===== P6: d1 = tanh(Wd1@h1 + bd1), 4 rows/block =====
    cstage(shv, f + F_H1 + p1*H, H);
    __syncthreads();
    if (wid < 4) {
      const int r = bid*4 + wid;
      float s6 = dotbf(wd1 + (size_t)r*H, shv, lane);
      s6 = red64(s6) + bd1[r];
      if (lane == 0) cstore(f + F_D1 + r, tanhf(s6));
    }
    abar(bar, bid, ++nb);                         // F: d1 ready

    // ===== P7: d = tanh(Wd2@d1 + bd2), 4 rows/block =====
    cstage(shv, f + F_D1, H);
    __syncthreads();
    if (wid < 4) {
      const int r = bid*4 + wid;
      float s7 = dotbf(wd2 + (size_t)r*H, shv, lane);
      s7 = red64(s7) + bd2[r];
      if (lane == 0) cstore(f + F_D + r, tanhf(s7));
    }
    abar(bar, bid, ++nb);                         // G: d ready

    // ===== P8: dec_out rows (bid, 80+bid) ; out ; next x =====
    if (bid < NMEL) {
      cstage(shv, f + F_D, H);
      __syncthreads();
      if (wid < 2) {
        const int r = wid*NMEL + bid;             // wid0: log_s, wid1: bb
        float s8 = dotf(Wc + (size_t)r*H, shv, lane);
        s8 = red64(s8) + bc[r];
        if (lane == 0) misc2[2 + wid] = s8;
      }
      __syncthreads();
      if (tid == 0) {
        const int idx = T_STEPS - 1 - s;
        const float r = residual[idx*NMEL + bid];
        const float o = (r - misc2[3]) * expf(-misc2[2]);
        out[idx*NMEL + bid] = o;
        cstore(f + F_X + bid, o);
      }
    }
    abar(bar, bid, ++nb);                         // H: x ready
  }
}

extern "C" void kernel_launch(void* const* d_in, const int* in_sizes, int n_in,
                              void* d_out, int out_size, void* d_ws, size_t ws_size,
                              hipStream_t stream) {
  const float* residual = (const float*)d_in[0];
  const float* text   = (const float*)d_in[1];
  const float* Wih_a  = (const float*)d_in[2];
  const float* Whh_a  = (const float*)d_in[3];
  const float* b_a    = (const float*)d_in[4];
  const float* Wq     = (const float*)d_in[5];
  const float* Wk     = (const float*)d_in[6];
  const float* Wv     = (const float*)d_in[7];
  const float* v_attn = (const float*)d_in[8];
  const float* Wih0   = (const float*)d_in[9];
  const float* Whh0   = (const float*)d_in[10];
  const float* b0     = (const float*)d_in[11];
  const float* Wih1   = (const float*)d_in[12];
  const float* Whh1   = (const float*)d_in[13];
  const float* b1     = (const float*)d_in[14];
  const float* Wd1    = (const float*)d_in[15];
  const float* bd1    = (const float*)d_in[16];
  const float* Wd2    = (const float*)d_in[17];
  const float* bd2    = (const float*)d_in[18];
  const float* Wc     = (const float*)d_in[19];
  const float* bc     = (const float*)d_in[20];
  const float* Wg     = (const float*)d_in[21];
  const float* bg     = (const float*)d_in[22];
  float* out = (float*)d_out;

  char* wsb = (char*)d_ws;
  ushortT*  u   = (ushortT*)wsb;
  float*    f   = (float*)(wsb + FBYTE);
  unsigned* bar = (unsigned*)(wsb + BBYTE);

  conv_bf16<<<1024, 256, 0, stream>>>(Wq,    u + O_WQ,   (size_t)ATT*H);
  conv_bf16<<<1024, 256, 0, stream>>>(Wih_a, u + O_WIHA, (size_t)4*H*NMEL);
  conv_bf16<<<1024, 256, 0, stream>>>(Wih0,  u + O_WIH0, (size_t)4*H*DIN);
  conv_bf16<<<1024, 256, 0, stream>>>(Whh1,  u + O_WHH1, (size_t)4*H*H);
  conv_bf16<<<1024, 256, 0, stream>>>(Wd1,   u + O_WD1,  (size_t)H*H);
  conv_bf16<<<1024, 256, 0, stream>>>(Wd2,   u + O_WD2,  (size_t)H*H);
  prep_kv<<<TXT, 256, 0, stream>>>(text, Wk, Wv, u + O_KEYS, u + O_VALS);
  prep_zero<<<64, 256, 0, stream>>>(f, bar);

  ar_persist<<<GBK, NT, 0, stream>>>(residual, Whh_a, Whh0, Wih1,
      b_a, v_attn, b0, b1, bd1, bd2, Wc, bc, Wg, bg, out, d_ws);
}